// Round 10
// baseline (1325.941 us; speedup 1.0000x reference)
//
#include <hip/hip_runtime.h>

// Problem constants
#define Bz 2048
#define Tz 336
#define Fz 10
#define H1 70
#define H2 21

typedef __attribute__((ext_vector_type(8))) short short8;   // 8 bf16 = 4 VGPR
typedef __attribute__((ext_vector_type(4))) float float4v;  // MFMA acc

#define MFMA16(a, b, c) __builtin_amdgcn_mfma_f32_16x16x32_bf16((a), (b), (c), 0, 0, 0)

__device__ __forceinline__ float sigf(float x) {
    return 1.0f / (1.0f + __expf(-x));
}
__device__ __forceinline__ float tanhfast(float x) {
    float t = __expf(2.0f * x);
    return 1.0f - 2.0f / (t + 1.0f);
}
__device__ __forceinline__ unsigned short f2bf(float v) {
    unsigned int u = __float_as_uint(v);
    u += 0x7FFFu + ((u >> 16) & 1u);
    return (unsigned short)(u >> 16);
}
__device__ __forceinline__ float bf2f(unsigned short s) {
    return __uint_as_float(((unsigned int)s) << 16);
}

// Fragment-order LDS offset (in shorts) for (col m, k):
// (m, k) lives at ((k>>3)*16 + m)*8 + (k&7)
__device__ __forceinline__ int frag_off(int m, int k) {
    return (k >> 3) * 128 + m * 8 + (k & 7);
}

// ---------------------------------------------------------------------------
// Layer 1 (MFMA, D = W x h): input F=10, hidden 70.
// Grid 512 = 2 dir x 256 tiles of 8 batch rows. Block = 256 threads = 4
// waves (<=256 thr blocks are PROVEN to co-reside ~2-3/CU — the >=512-thr
// blocks of rounds 5-9 never did; occupancy showed 1 block/CU and round 9's
// 512-block grid ran as 2 serial passes).
// 18 M-tiles over 4 waves: waves 0,1 -> 5 tiles {w,w+4,w+8,w+12,w+16};
// waves 2,3 -> 4 tiles {w,w+4,w+8,w+12} + x staging.
//   K: 0..69 = h, 70..79 = x, 80 = bias slot (B col value 1.0), 81..95 = 0.
// B cols: 8 batch rows duplicated into cols 0..7 and 8..15 (every D col is
// a valid batch row). Dual-tile epilogue per tile pair: lane n<8 -> first
// tile cell (m=n,u), n>=8 -> second tile cell (m=n-8,u); 5th tile epilogue
// on lanes n<8. One barrier/step; x prefetch depth 2.
// y1 layout: [T][256][140][8] bf16 — block-private dense 2240 B/step rows.
// ---------------------------------------------------------------------------
__global__ __launch_bounds__(256, 2) void k_lstm1(
    const float* __restrict__ x,
    const float* __restrict__ wih_f, const float* __restrict__ whh_f,
    const float* __restrict__ bih_f, const float* __restrict__ bhh_f,
    const float* __restrict__ wih_b, const float* __restrict__ whh_b,
    const float* __restrict__ bih_b, const float* __restrict__ bhh_b,
    unsigned short* __restrict__ y1)
{
    __shared__ short hB_hi[2][1536];   // 96 k x 16 cols, frag order, dbuf

    const int tb8 = blockIdx.x & 255;
    const int dir = blockIdx.x >> 8;
    const int b0  = tb8 << 3;
    const float* wih = dir ? wih_b : wih_f;
    const float* whh = dir ? whh_b : whh_f;
    const float* bih = dir ? bih_b : bih_f;
    const float* bhh = dir ? bhh_b : bhh_f;

    const int tid  = threadIdx.x;
    const int wv   = tid >> 6;        // 0..3
    const int lane = tid & 63;
    const int n    = lane & 15;
    const int quad = lane >> 4;
    const int NT   = (wv < 2) ? 5 : 4;

    // ---- W-side (A-operand) preload: tiles p = wv + 4i, hi+lo bf16 ----
    short8 whi[5][3], wlo[5][3];
    const int g_ = n & 3;
#pragma unroll
    for (int i = 0; i < 5; ++i) {
        if (i < NT) {
            const int p  = wv + 4 * i;
            const int uu = 4 * p + (n >> 2);
#pragma unroll
            for (int q = 0; q < 3; ++q) {
#pragma unroll
                for (int j = 0; j < 8; ++j) {
                    int k = q * 32 + quad * 8 + j;
                    float v = 0.0f;
                    if (uu < H1) {
                        int row = g_ * H1 + uu;
                        if (k < H1)        v = whh[row * H1 + k];
                        else if (k < 80)   v = wih[row * Fz + (k - H1)];
                        else if (k == 80)  v = bih[row] + bhh[row];
                    }
                    unsigned short hi = f2bf(v);
                    unsigned short lo = f2bf(v - bf2f(hi));
                    whi[i][q][j] = (short)hi;
                    wlo[i][q][j] = (short)lo;
                }
            }
        }
    }

    // ---- init LDS ----
    for (int e = tid; e < 1536; e += 256) {
        hB_hi[0][e] = 0; hB_hi[1][e] = 0;
    }
    __syncthreads();
    if (tid < 16) {
        int off = 1280 + tid * 8;       // frag_off(tid, 80)
        hB_hi[0][off] = (short)0x3F80;  // bf16(1.0) bias const, all 16 cols
        hB_hi[1][off] = (short)0x3F80;
    }

    // ---- stagers: threads 128..255 (waves 2,3 — the 4-tile waves) ----
    const int st  = tid - 128;
    const bool stg = (st >= 0 && st < 80);   // 8 rows x 10 features
    int sm = 0, sf = 0;
    if (stg) { sm = st / Fz; sf = st % Fz; }

    // prologue: stage x(t0) into buf 0 (both col copies); preload x(t1)
    float xv = 0.0f;
    {
        const int t0 = dir ? (Tz - 1) : 0;
        if (stg) {
            float v = x[((size_t)(b0 + sm) * Tz + t0) * Fz + sf];
            unsigned short hv = f2bf(v);
            hB_hi[0][frag_off(sm,     H1 + sf)] = (short)hv;
            hB_hi[0][frag_off(sm + 8, H1 + sf)] = (short)hv;
            const int t1 = dir ? (Tz - 2) : 1;
            xv = x[((size_t)(b0 + sm) * Tz + t1) * Fz + sf];
        }
    }

    const int m8   = n & 7;
    const bool selB = (n >> 3) != 0;

    float cst[3];
    cst[0] = 0.0f; cst[1] = 0.0f; cst[2] = 0.0f;

    for (int step = 0; step < Tz; ++step) {
        const int t  = dir ? (Tz - 1 - step) : step;
        const int pp = step & 1;
        __syncthreads();   // only barrier: buf[pp] complete, buf[pp^1] free

        // write x(t+1) from regs (both copies), then issue load x(t+2)
        if (stg && step + 1 < Tz) {
            unsigned short hv = f2bf(xv);
            hB_hi[pp ^ 1][frag_off(sm,     H1 + sf)] = (short)hv;
            hB_hi[pp ^ 1][frag_off(sm + 8, H1 + sf)] = (short)hv;
        }
        if (stg && step + 2 < Tz) {
            const int t2 = dir ? (t - 2) : (t + 2);
            xv = x[((size_t)(b0 + sm) * Tz + t2) * Fz + sf];
        }

        // B-operand frags from LDS (hi only)
        short8 bhi[3];
#pragma unroll
        for (int q = 0; q < 3; ++q)
            bhi[q] = *(const short8*)&hB_hi[pp][q * 512 + lane * 8];

        // MFMA: per tile 6 products (hi chain + lo chain)
        float4v accA[5], accB[5];
#pragma unroll
        for (int i = 0; i < 5; ++i) {
            accA[i] = (float4v){0.f, 0.f, 0.f, 0.f};
            accB[i] = (float4v){0.f, 0.f, 0.f, 0.f};
        }
#pragma unroll
        for (int i = 0; i < 5; ++i) {
            if (i < NT) {
                accA[i] = MFMA16(whi[i][0], bhi[0], accA[i]);
                accB[i] = MFMA16(wlo[i][0], bhi[0], accB[i]);
                accA[i] = MFMA16(whi[i][1], bhi[1], accA[i]);
                accB[i] = MFMA16(wlo[i][1], bhi[1], accB[i]);
                accA[i] = MFMA16(whi[i][2], bhi[2], accA[i]);
                accB[i] = MFMA16(wlo[i][2], bhi[2], accB[i]);
            }
        }

        const size_t ybase = ((size_t)t * 256 + tb8) * 1120 + (size_t)dir * H1 * 8;

        // dual-tile epilogue: pair slots (0,1) and (2,3)
#pragma unroll
        for (int s = 0; s < 2; ++s) {
            const int ia = 2 * s, ib = 2 * s + 1;
            const int u = 4 * (wv + 4 * (selB ? ib : ia)) + quad;   // <= 63
            float gi = selB ? (accA[ib][0] + accB[ib][0]) : (accA[ia][0] + accB[ia][0]);
            float gf = selB ? (accA[ib][1] + accB[ib][1]) : (accA[ia][1] + accB[ia][1]);
            float gc = selB ? (accA[ib][2] + accB[ib][2]) : (accA[ia][2] + accB[ia][2]);
            float go = selB ? (accA[ib][3] + accB[ib][3]) : (accA[ia][3] + accB[ia][3]);
            float cn = sigf(gf) * cst[s] + sigf(gi) * tanhfast(gc);
            float h  = sigf(go) * tanhfast(cn);
            cst[s] = cn;
            unsigned short hh = f2bf(h);
            hB_hi[pp ^ 1][frag_off(m8,     u)] = (short)hh;
            hB_hi[pp ^ 1][frag_off(m8 + 8, u)] = (short)hh;
            y1[ybase + (size_t)u * 8 + m8] = hh;
        }
        // 5th tile (waves 0,1): lanes n<8 only
        if (wv < 2 && n < 8) {
            const int u = 4 * (wv + 16) + quad;
            if (u < H1) {
                float gi = accA[4][0] + accB[4][0];
                float gf = accA[4][1] + accB[4][1];
                float gc = accA[4][2] + accB[4][2];
                float go = accA[4][3] + accB[4][3];
                float cn = sigf(gf) * cst[2] + sigf(gi) * tanhfast(gc);
                float h  = sigf(go) * tanhfast(cn);
                cst[2] = cn;
                unsigned short hh = f2bf(h);
                hB_hi[pp ^ 1][frag_off(m8,     u)] = (short)hh;
                hB_hi[pp ^ 1][frag_off(m8 + 8, u)] = (short)hh;
                y1[ybase + (size_t)u * 8 + m8] = hh;
            }
        }
    }
}

// ---------------------------------------------------------------------------
// Layer 2 (MFMA, D = W x h): input 140 (bf16 y1 [T][256][140][8]), hidden 21.
// Grid 512 = 2 dir x 256 tiles of 8 rows. Block = 256 threads = 4 waves:
// waves 0..2 compute 2 tiles each ({w, w+3} of 6 tiles — perfect balance,
// dual epilogue = ONE transcendental block per lane); wave 3 stages x.
//   K: 0..20 = h, 21 = bias slot, 22..31 = 0, 32..171 = x, 172..191 = 0.
// B cols: 8 rows duplicated into both halves. h/x hi-only; W-lo for chunk 0.
// ---------------------------------------------------------------------------
__global__ __launch_bounds__(256, 2) void k_lstm2(
    const unsigned short* __restrict__ y1,
    const float* __restrict__ wih_f, const float* __restrict__ whh_f,
    const float* __restrict__ bih_f, const float* __restrict__ bhh_f,
    const float* __restrict__ wih_b, const float* __restrict__ whh_b,
    const float* __restrict__ bih_b, const float* __restrict__ bhh_b,
    unsigned short* __restrict__ y2)   // [B][T][42] bf16
{
    __shared__ short hB_hi[2][3072];   // 192 k x 16 cols

    const int tb8 = blockIdx.x & 255;
    const int dir = blockIdx.x >> 8;
    const int b0  = tb8 << 3;
    const float* wih = dir ? wih_b : wih_f;
    const float* whh = dir ? whh_b : whh_f;
    const float* bih = dir ? bih_b : bih_f;
    const float* bhh = dir ? bhh_b : bhh_f;

    const int tid  = threadIdx.x;
    const int wv   = tid >> 6;
    const int lane = tid & 63;
    const int n    = lane & 15;
    const int quad = lane >> 4;
    const bool comp = (wv < 3);

    // ---- W-side preload (waves 0..2): tiles {wv, wv+3}; hi all, lo chunk0 ----
    short8 whi[2][6], wlo0[2];
    const int g_ = n & 3;
    if (comp) {
#pragma unroll
        for (int tt = 0; tt < 2; ++tt) {
            const int p  = wv + 3 * tt;
            const int uu = 4 * p + (n >> 2);
#pragma unroll
            for (int q = 0; q < 6; ++q) {
#pragma unroll
                for (int j = 0; j < 8; ++j) {
                    int k = q * 32 + quad * 8 + j;
                    float v = 0.0f;
                    if (uu < H2) {
                        int row = g_ * H2 + uu;
                        if (k < H2)                   v = whh[row * H2 + k];
                        else if (k == 21)             v = bih[row] + bhh[row];
                        else if (k >= 32 && k < 172)  v = wih[row * 140 + (k - 32)];
                    }
                    unsigned short hi = f2bf(v);
                    whi[tt][q][j] = (short)hi;
                    if (q == 0) wlo0[tt][j] = (short)f2bf(v - bf2f(hi));
                }
            }
        }
    }

    // ---- init LDS ----
    for (int e = tid; e < 3072; e += 256) { hB_hi[0][e] = 0; hB_hi[1][e] = 0; }
    __syncthreads();
    if (tid < 16) {
        int off = frag_off(tid, 21);
        hB_hi[0][off] = (short)0x3F80;   // bias const 1.0, all 16 cols
        hB_hi[1][off] = (short)0x3F80;
    }

    // ---- stager wave 3: tasks u = lane + 64i (i=0..2, u<140); 16B loads ----
    short8 xr[3];

    // prologue: stage x(t0) into buf 0; preload x(t1)
    if (wv == 3) {
        const int t0 = dir ? (Tz - 1) : 0;
        const int t1 = dir ? (Tz - 2) : 1;
#pragma unroll
        for (int i = 0; i < 3; ++i) {
            int u = lane + 64 * i;
            if (u < 140) {
                short8 v = *(const short8*)(y1 + ((size_t)t0 * 256 + tb8) * 1120 + u * 8);
#pragma unroll
                for (int m = 0; m < 8; ++m) {
                    hB_hi[0][frag_off(m,     32 + u)] = v[m];
                    hB_hi[0][frag_off(m + 8, 32 + u)] = v[m];
                }
                xr[i] = *(const short8*)(y1 + ((size_t)t1 * 256 + tb8) * 1120 + u * 8);
            }
        }
    }

    const int m8   = n & 7;
    const bool selB = (n >> 3) != 0;

    float cst = 0.0f;

    for (int step = 0; step < Tz; ++step) {
        const int t  = dir ? (Tz - 1 - step) : step;
        const int pp = step & 1;
        __syncthreads();

        if (wv == 3) {
            // write x(t+1) from regs (both col copies), then load x(t+2)
            if (step + 1 < Tz) {
#pragma unroll
                for (int i = 0; i < 3; ++i) {
                    int u = lane + 64 * i;
                    if (u < 140) {
#pragma unroll
                        for (int m = 0; m < 8; ++m) {
                            hB_hi[pp ^ 1][frag_off(m,     32 + u)] = xr[i][m];
                            hB_hi[pp ^ 1][frag_off(m + 8, 32 + u)] = xr[i][m];
                        }
                    }
                }
            }
            if (step + 2 < Tz) {
                const int t2 = dir ? (t - 2) : (t + 2);
#pragma unroll
                for (int i = 0; i < 3; ++i) {
                    int u = lane + 64 * i;
                    if (u < 140)
                        xr[i] = *(const short8*)(y1 + ((size_t)t2 * 256 + tb8) * 1120 + u * 8);
                }
            }
        } else {
            // B-operand frags (hi only)
            short8 bhi[6];
#pragma unroll
            for (int q = 0; q < 6; ++q)
                bhi[q] = *(const short8*)&hB_hi[pp][q * 512 + lane * 8];

            // per tile: 7 products in 2 chains
            float4v accA[2], accB[2];
#pragma unroll
            for (int tt = 0; tt < 2; ++tt) {
                accA[tt] = (float4v){0.f, 0.f, 0.f, 0.f};
                accB[tt] = (float4v){0.f, 0.f, 0.f, 0.f};
                accA[tt] = MFMA16(whi[tt][0], bhi[0], accA[tt]);
                accB[tt] = MFMA16(wlo0[tt],   bhi[0], accB[tt]);
                accA[tt] = MFMA16(whi[tt][2], bhi[2], accA[tt]);
                accB[tt] = MFMA16(whi[tt][1], bhi[1], accB[tt]);
                accA[tt] = MFMA16(whi[tt][4], bhi[4], accA[tt]);
                accB[tt] = MFMA16(whi[tt][3], bhi[3], accB[tt]);
                accB[tt] = MFMA16(whi[tt][5], bhi[5], accB[tt]);
            }

            // dual-tile epilogue: lane n<8 -> tile wv, n>=8 -> tile wv+3
            const int u = (selB ? (12 + 4 * wv) : (4 * wv)) + quad;
            if (u < H2) {
                float gi = selB ? (accA[1][0] + accB[1][0]) : (accA[0][0] + accB[0][0]);
                float gf = selB ? (accA[1][1] + accB[1][1]) : (accA[0][1] + accB[0][1]);
                float gc = selB ? (accA[1][2] + accB[1][2]) : (accA[0][2] + accB[0][2]);
                float go = selB ? (accA[1][3] + accB[1][3]) : (accA[0][3] + accB[0][3]);
                float cn = sigf(gf) * cst + sigf(gi) * tanhfast(gc);
                float h  = sigf(go) * tanhfast(cn);
                cst = cn;
                unsigned short hh = f2bf(h);
                hB_hi[pp ^ 1][frag_off(m8,     u)] = (short)hh;
                hB_hi[pp ^ 1][frag_off(m8 + 8, u)] = (short)hh;
                y2[((size_t)(b0 + m8) * Tz + t) * 42 + dir * H2 + u] = hh;
            }
        }
    }
}

// ---------------------------------------------------------------------------
// Dense head: thread per (b,t). Weights via uniform scalar loads.
// ---------------------------------------------------------------------------
__global__ __launch_bounds__(256) void k_dense(
    const unsigned short* __restrict__ y2,
    const float* __restrict__ wd1, const float* __restrict__ bd1,
    const float* __restrict__ wd2, const float* __restrict__ bd2,
    const float* __restrict__ wo,  const float* __restrict__ bo,
    float* __restrict__ out)
{
    int idx = blockIdx.x * 256 + threadIdx.x;
    if (idx >= Bz * Tz) return;
    const unsigned int* row = (const unsigned int*)&y2[(size_t)idx * 42];

    float v[42];
#pragma unroll
    for (int j = 0; j < 21; ++j) {
        unsigned int p = row[j];
        v[2 * j]     = bf2f((unsigned short)(p & 0xFFFFu));
        v[2 * j + 1] = bf2f((unsigned short)(p >> 16));
    }

    float h1[30];
#pragma unroll
    for (int o = 0; o < 30; ++o) {
        float s = bd1[o];
#pragma unroll
        for (int j = 0; j < 42; ++j) s = fmaf(v[j], wd1[o * 42 + j], s);
        h1[o] = fmaxf(s, 0.0f);
    }
    float outv = bo[0];
#pragma unroll
    for (int o = 0; o < 20; ++o) {
        float s = bd2[o];
#pragma unroll
        for (int j = 0; j < 30; ++j) s = fmaf(h1[j], wd2[o * 30 + j], s);
        outv = fmaf(fmaxf(s, 0.0f), wo[o], outv);
    }
    out[idx] = outv;
}

// ---------------------------------------------------------------------------
extern "C" void kernel_launch(void* const* d_in, const int* in_sizes, int n_in,
                              void* d_out, int out_size, void* d_ws, size_t ws_size,
                              hipStream_t stream)
{
    const float* x      = (const float*)d_in[0];
    const float* w1f_ih = (const float*)d_in[1];
    const float* w1f_hh = (const float*)d_in[2];
    const float* b1f_ih = (const float*)d_in[3];
    const float* b1f_hh = (const float*)d_in[4];
    const float* w1b_ih = (const float*)d_in[5];
    const float* w1b_hh = (const float*)d_in[6];
    const float* b1b_ih = (const float*)d_in[7];
    const float* b1b_hh = (const float*)d_in[8];
    const float* w2f_ih = (const float*)d_in[9];
    const float* w2f_hh = (const float*)d_in[10];
    const float* b2f_ih = (const float*)d_in[11];
    const float* b2f_hh = (const float*)d_in[12];
    const float* w2b_ih = (const float*)d_in[13];
    const float* w2b_hh = (const float*)d_in[14];
    const float* b2b_ih = (const float*)d_in[15];
    const float* b2b_hh = (const float*)d_in[16];
    const float* wd1    = (const float*)d_in[17];
    const float* bd1    = (const float*)d_in[18];
    const float* wd2    = (const float*)d_in[19];
    const float* bd2    = (const float*)d_in[20];
    const float* wo     = (const float*)d_in[21];
    const float* bo     = (const float*)d_in[22];
    float* out = (float*)d_out;

    // Workspace: y1 bf16 [T][256][140][8] (192.7 MB) + y2 bf16 [B][T][42] (57.8 MB)
    const size_t y1_elems = (size_t)Tz * 256 * 1120;
    const size_t y2_elems = (size_t)Bz * Tz * 42;
    if (ws_size < (y1_elems + y2_elems) * 2) return;

    unsigned short* y1 = (unsigned short*)d_ws;
    unsigned short* y2 = y1 + y1_elems;

    hipLaunchKernelGGL(k_lstm1, dim3(512), dim3(256), 0, stream,
                       x, w1f_ih, w1f_hh, b1f_ih, b1f_hh,
                       w1b_ih, w1b_hh, b1b_ih, b1b_hh, y1);
    hipLaunchKernelGGL(k_lstm2, dim3(512), dim3(256), 0, stream,
                       y1, w2f_ih, w2f_hh, b2f_ih, b2f_hh,
                       w2b_ih, w2b_hh, b2b_ih, b2b_hh, y2);
    hipLaunchKernelGGL(k_dense, dim3((Bz * Tz + 255) / 256), dim3(256), 0, stream,
                       y2, wd1, bd1, wd2, bd2, wo, bo, out);
}

// Round 11
// 720.589 us; speedup vs baseline: 1.8401x; 1.8401x over previous
//
#include <hip/hip_runtime.h>

// Problem constants
#define Bz 2048
#define Tz 336
#define Fz 10
#define H1 70
#define H2 21

typedef __attribute__((ext_vector_type(8))) short short8;   // 8 bf16 = 4 VGPR
typedef __attribute__((ext_vector_type(4))) float float4v;  // MFMA acc

#define MFMA16(a, b, c) __builtin_amdgcn_mfma_f32_16x16x32_bf16((a), (b), (c), 0, 0, 0)

__device__ __forceinline__ float sigf(float x) {
    return 1.0f / (1.0f + __expf(-x));
}
__device__ __forceinline__ float tanhfast(float x) {
    float t = __expf(2.0f * x);
    return 1.0f - 2.0f / (t + 1.0f);
}
__device__ __forceinline__ unsigned short f2bf(float v) {
    unsigned int u = __float_as_uint(v);
    u += 0x7FFFu + ((u >> 16) & 1u);
    return (unsigned short)(u >> 16);
}
__device__ __forceinline__ float bf2f(unsigned short s) {
    return __uint_as_float(((unsigned int)s) << 16);
}

// Fragment-order LDS offset (in shorts) for (col m, k):
// (m, k) lives at ((k>>3)*16 + m)*8 + (k&7)
__device__ __forceinline__ int frag_off(int m, int k) {
    return (k >> 3) * 128 + m * 8 + (k & 7);
}

// ---------------------------------------------------------------------------
// Layer 1 (MFMA, D = W x h): input F=10, hidden 70.  [round-7 structure]
// Grid 256 = 2 dir x 128 tiles of 16 batch rows. 1024 threads = 16 waves.
// 18 M-tiles: wave w owns tile w; waves 0,1 also own tiles 16,17.
//   K: 0..69 = h, 70..79 = x, 80 = bias slot (B col 1.0), 81..95 = 0.
// h bf16 hi-only in LDS; W hi+lo in registers (6 MFMA/tile). One barrier per
// step, double-buffered B-LDS, x prefetch depth 2.
// NEW vs round 7: step loop unrolled x2 with pp as a literal (all LDS
// addresses loop-invariant) + strided pointer increments for x / y1 (no
// per-step t-indexed address math). Bit-identical arithmetic.
// y1 layout: [T][128][140][16] bf16.
// ---------------------------------------------------------------------------
__global__ __launch_bounds__(1024, 4) void k_lstm1(
    const float* __restrict__ x,
    const float* __restrict__ wih_f, const float* __restrict__ whh_f,
    const float* __restrict__ bih_f, const float* __restrict__ bhh_f,
    const float* __restrict__ wih_b, const float* __restrict__ whh_b,
    const float* __restrict__ bih_b, const float* __restrict__ bhh_b,
    unsigned short* __restrict__ y1)
{
    __shared__ short hB_hi[2][1536];   // 96 k x 16 batch, frag order, dbuf

    const int tb  = blockIdx.x & 127;
    const int dir = blockIdx.x >> 7;
    const int b0  = tb << 4;
    const float* wih = dir ? wih_b : wih_f;
    const float* whh = dir ? whh_b : whh_f;
    const float* bih = dir ? bih_b : bih_f;
    const float* bhh = dir ? bhh_b : bhh_f;

    const int tid  = threadIdx.x;
    const int wv   = tid >> 6;
    const int lane = tid & 63;
    const int n    = lane & 15;
    const int quad = lane >> 4;
    const int NT1  = (wv < 2) ? 2 : 1;   // tiles this wave owns

    // ---- W-side (A-operand) preload, hi+lo bf16 ----
    short8 whi[2][3], wlo[2][3];
    const int g_ = n & 3;
#pragma unroll
    for (int tt = 0; tt < 2; ++tt) {
        if (tt < NT1) {
            const int p  = wv + 16 * tt;
            const int uu = 4 * p + (n >> 2);
#pragma unroll
            for (int q = 0; q < 3; ++q) {
#pragma unroll
                for (int j = 0; j < 8; ++j) {
                    int k = q * 32 + quad * 8 + j;
                    float v = 0.0f;
                    if (uu < H1) {
                        int row = g_ * H1 + uu;
                        if (k < H1)        v = whh[row * H1 + k];
                        else if (k < 80)   v = wih[row * Fz + (k - H1)];
                        else if (k == 80)  v = bih[row] + bhh[row];
                    }
                    unsigned short hi = f2bf(v);
                    unsigned short lo = f2bf(v - bf2f(hi));
                    whi[tt][q][j] = (short)hi;
                    wlo[tt][q][j] = (short)lo;
                }
            }
        }
    }

    // ---- init LDS ----
    for (int e = tid; e < 1536; e += 1024) {
        hB_hi[0][e] = 0; hB_hi[1][e] = 0;
    }
    __syncthreads();
    if (tid < 16) {
        int off = 1280 + tid * 8;       // frag_off(tid, 80)
        hB_hi[0][off] = (short)0x3F80;  // bf16(1.0) bias const
        hB_hi[1][off] = (short)0x3F80;
    }

    // ---- stagers: es in [0,160) -> (m, f), threads 864..1023 ----
    const int es = tid - 864;
    const bool stg = (es >= 0 && es < 160);
    int sm = 0, sf = 0;
    if (stg) { sm = es / Fz; sf = es % Fz; }

    const int tstep = dir ? -1 : 1;
    const int t0    = dir ? (Tz - 1) : 0;

    // prologue: stage x(t0) into buf 0; preload x(t1) into regs
    float xv = 0.0f;
    if (stg) {
        float v = x[((size_t)(b0 + sm) * Tz + t0) * Fz + sf];
        hB_hi[0][frag_off(sm, H1 + sf)] = (short)f2bf(v);
        xv = x[((size_t)(b0 + sm) * Tz + t0 + tstep) * Fz + sf];
    }
    // strided pointers (advance by tstep*stride per step)
    const float* xp = x + ((size_t)(b0 + sm) * Tz + t0 + 2 * tstep) * Fz + sf;
    const ptrdiff_t xinc = (ptrdiff_t)tstep * Fz;
    unsigned short* yp = y1 + (((size_t)t0 * 128 + tb) * 140 + dir * H1) * 16 + n;
    const ptrdiff_t yinc = (ptrdiff_t)tstep * (140 * 128 * 16);

    // hoisted LDS write offsets (loop-invariant)
    const int xoff = frag_off(sm, H1 + sf);
    int hoff[2];
#pragma unroll
    for (int tt = 0; tt < 2; ++tt) hoff[tt] = frag_off(n, 4 * (wv + 16 * tt) + quad);

    float cst[2];
    cst[0] = 0.0f; cst[1] = 0.0f;

    // one step; pp is a literal at each call site -> all LDS addrs invariant
    auto body = [&](int step, const int pp) __attribute__((always_inline)) {
        __syncthreads();   // buf[pp] complete, buf[pp^1] free

        if (stg && step + 1 < Tz) {
            hB_hi[pp ^ 1][xoff] = (short)f2bf(xv);
        }
        if (stg && step + 2 < Tz) {
            xv = *xp;
        }

        short8 bhi[3];
#pragma unroll
        for (int q = 0; q < 3; ++q)
            bhi[q] = *(const short8*)&hB_hi[pp][q * 512 + lane * 8];

        float4v accA[2], accB[2];
#pragma unroll
        for (int tt = 0; tt < 2; ++tt) {
            accA[tt] = (float4v){0.f, 0.f, 0.f, 0.f};
            accB[tt] = (float4v){0.f, 0.f, 0.f, 0.f};
        }
#pragma unroll
        for (int tt = 0; tt < 2; ++tt) {
            if (tt < NT1) {
                accA[tt] = MFMA16(whi[tt][0], bhi[0], accA[tt]);
                accB[tt] = MFMA16(wlo[tt][0], bhi[0], accB[tt]);
                accA[tt] = MFMA16(whi[tt][1], bhi[1], accA[tt]);
                accB[tt] = MFMA16(wlo[tt][1], bhi[1], accB[tt]);
                accA[tt] = MFMA16(whi[tt][2], bhi[2], accA[tt]);
                accB[tt] = MFMA16(wlo[tt][2], bhi[2], accB[tt]);
            }
        }

#pragma unroll
        for (int tt = 0; tt < 2; ++tt) {
            if (tt < NT1) {
                const int u = 4 * (wv + 16 * tt) + quad;
                if (u < H1) {
                    float gi = accA[tt][0] + accB[tt][0];
                    float gf = accA[tt][1] + accB[tt][1];
                    float gc = accA[tt][2] + accB[tt][2];
                    float go = accA[tt][3] + accB[tt][3];
                    float cn = sigf(gf) * cst[tt] + sigf(gi) * tanhfast(gc);
                    float h  = sigf(go) * tanhfast(cn);
                    cst[tt] = cn;
                    unsigned short hh = f2bf(h);
                    hB_hi[pp ^ 1][hoff[tt]] = (short)hh;
                    yp[u * 16] = hh;
                }
            }
        }
        xp += xinc;
        yp += yinc;
    };

    for (int step = 0; step < Tz; step += 2) {
        body(step, 0);
        body(step + 1, 1);
    }
}

// ---------------------------------------------------------------------------
// Layer 2 (MFMA, D = W x h): input 140 (bf16 y1 [T][128][140][16]), hidden 21.
// [round-7 structure] Grid 256 = 2 dir x 128 tiles of 16 rows. 512 thr = 8
// waves: waves 0..5 compute tile p = wv (u = 4p+quad); threads 232..511
// stage x (16B vector loads). K: 0..20 = h, 21 = bias, 32..171 = x.
// h/x hi-only; W-lo for chunk 0 only: 7 MFMA/wave.
// NEW: unroll x2 (pp literal) + strided pointers. Bit-identical arithmetic.
// ---------------------------------------------------------------------------
__global__ __launch_bounds__(512, 2) void k_lstm2(
    const unsigned short* __restrict__ y1,
    const float* __restrict__ wih_f, const float* __restrict__ whh_f,
    const float* __restrict__ bih_f, const float* __restrict__ bhh_f,
    const float* __restrict__ wih_b, const float* __restrict__ whh_b,
    const float* __restrict__ bih_b, const float* __restrict__ bhh_b,
    unsigned short* __restrict__ y2)   // [B][T][42] bf16
{
    __shared__ short hB_hi[2][3072];   // 192 k x 16 batch

    const int tb  = blockIdx.x & 127;
    const int dir = blockIdx.x >> 7;
    const int b0  = tb << 4;
    const float* wih = dir ? wih_b : wih_f;
    const float* whh = dir ? whh_b : whh_f;
    const float* bih = dir ? bih_b : bih_f;
    const float* bhh = dir ? bhh_b : bhh_f;

    const int tid  = threadIdx.x;
    const int wv   = tid >> 6;
    const int lane = tid & 63;
    const int n    = lane & 15;
    const int quad = lane >> 4;
    const bool comp = (wv < 6);

    // ---- W-side preload (waves 0..5): hi all chunks, lo chunk 0 ----
    short8 whi[6], wlo0;
    const int g_ = n & 3;
    if (comp) {
        const int uu = 4 * wv + (n >> 2);
#pragma unroll
        for (int q = 0; q < 6; ++q) {
#pragma unroll
            for (int j = 0; j < 8; ++j) {
                int k = q * 32 + quad * 8 + j;
                float v = 0.0f;
                if (uu < H2) {
                    int row = g_ * H2 + uu;
                    if (k < H2)                   v = whh[row * H2 + k];
                    else if (k == 21)             v = bih[row] + bhh[row];
                    else if (k >= 32 && k < 172)  v = wih[row * 140 + (k - 32)];
                }
                unsigned short hi = f2bf(v);
                whi[q][j] = (short)hi;
                if (q == 0) wlo0[j] = (short)f2bf(v - bf2f(hi));
            }
        }
    }

    // ---- init LDS ----
    for (int e = tid; e < 3072; e += 512) { hB_hi[0][e] = 0; hB_hi[1][e] = 0; }
    __syncthreads();
    if (tid < 16) {
        int off = frag_off(tid, 21);
        hB_hi[0][off] = (short)0x3F80;   // bias const 1.0
        hB_hi[1][off] = (short)0x3F80;
    }

    // ---- stager threads: es in [0,280); each loads 16B (8 ushorts) ----
    const int es = tid - 232;
    const bool stg = (es >= 0 && es < 280);

    const int tstep = dir ? -1 : 1;
    const int t0    = dir ? (Tz - 1) : 0;

    // prologue: stage x(t0) into buf 0; preload x(t1)
    short8 xr = (short8){0,0,0,0,0,0,0,0};
    if (stg) {
        short8 v = *(const short8*)(y1 + ((size_t)t0 * 128 + tb) * 2240 + es * 8);
#pragma unroll
        for (int j = 0; j < 8; ++j) {
            int idx = es * 8 + j;
            hB_hi[0][frag_off(idx & 15, 32 + (idx >> 4))] = v[j];
        }
        xr = *(const short8*)(y1 + ((size_t)(t0 + tstep) * 128 + tb) * 2240 + es * 8);
    }
    // strided pointers
    const unsigned short* srcp =
        y1 + ((size_t)(t0 + 2 * tstep) * 128 + tb) * 2240 + es * 8;
    const ptrdiff_t sinc = (ptrdiff_t)tstep * (128 * 2240);
    unsigned short* yp2 = y2 + ((size_t)(b0 + n) * Tz + t0) * 42 + dir * H2;
    const ptrdiff_t yinc = (ptrdiff_t)tstep * 42;

    // hoisted LDS offsets
    int xoffs[8];
#pragma unroll
    for (int j = 0; j < 8; ++j) {
        int idx = es * 8 + j;
        xoffs[j] = frag_off(idx & 15, 32 + (idx >> 4));
    }
    const int u     = 4 * wv + quad;
    const int hoffc = frag_off(n, (u < H2) ? u : 0);

    float cst = 0.0f;

    auto body = [&](int step, const int pp) __attribute__((always_inline)) {
        __syncthreads();

        if (stg && step + 1 < Tz) {
#pragma unroll
            for (int j = 0; j < 8; ++j)
                hB_hi[pp ^ 1][xoffs[j]] = xr[j];
        }
        if (stg && step + 2 < Tz) {
            xr = *(const short8*)srcp;
        }

        if (comp) {
            short8 bhi[6];
#pragma unroll
            for (int q = 0; q < 6; ++q)
                bhi[q] = *(const short8*)&hB_hi[pp][q * 512 + lane * 8];

            float4v accA = (float4v){0.f, 0.f, 0.f, 0.f};
            float4v accB = (float4v){0.f, 0.f, 0.f, 0.f};
            accA = MFMA16(whi[0], bhi[0], accA);
            accB = MFMA16(wlo0,   bhi[0], accB);
            accA = MFMA16(whi[2], bhi[2], accA);
            accB = MFMA16(whi[1], bhi[1], accB);
            accA = MFMA16(whi[4], bhi[4], accA);
            accB = MFMA16(whi[3], bhi[3], accB);
            accB = MFMA16(whi[5], bhi[5], accB);

            if (u < H2) {
                float gi = accA[0] + accB[0];
                float gf = accA[1] + accB[1];
                float gc = accA[2] + accB[2];
                float go = accA[3] + accB[3];
                float cn = sigf(gf) * cst + sigf(gi) * tanhfast(gc);
                float h  = sigf(go) * tanhfast(cn);
                cst = cn;
                unsigned short hh = f2bf(h);
                hB_hi[pp ^ 1][hoffc] = (short)hh;
                yp2[u] = hh;
            }
        }
        srcp += sinc;
        yp2  += yinc;
    };

    for (int step = 0; step < Tz; step += 2) {
        body(step, 0);
        body(step + 1, 1);
    }
}

// ---------------------------------------------------------------------------
// Dense head: thread per (b,t). Weights via uniform scalar loads.
// ---------------------------------------------------------------------------
__global__ __launch_bounds__(256) void k_dense(
    const unsigned short* __restrict__ y2,
    const float* __restrict__ wd1, const float* __restrict__ bd1,
    const float* __restrict__ wd2, const float* __restrict__ bd2,
    const float* __restrict__ wo,  const float* __restrict__ bo,
    float* __restrict__ out)
{
    int idx = blockIdx.x * 256 + threadIdx.x;
    if (idx >= Bz * Tz) return;
    const unsigned int* row = (const unsigned int*)&y2[(size_t)idx * 42];

    float v[42];
#pragma unroll
    for (int j = 0; j < 21; ++j) {
        unsigned int p = row[j];
        v[2 * j]     = bf2f((unsigned short)(p & 0xFFFFu));
        v[2 * j + 1] = bf2f((unsigned short)(p >> 16));
    }

    float h1[30];
#pragma unroll
    for (int o = 0; o < 30; ++o) {
        float s = bd1[o];
#pragma unroll
        for (int j = 0; j < 42; ++j) s = fmaf(v[j], wd1[o * 42 + j], s);
        h1[o] = fmaxf(s, 0.0f);
    }
    float outv = bo[0];
#pragma unroll
    for (int o = 0; o < 20; ++o) {
        float s = bd2[o];
#pragma unroll
        for (int j = 0; j < 30; ++j) s = fmaf(h1[j], wd2[o * 30 + j], s);
        outv = fmaf(fmaxf(s, 0.0f), wo[o], outv);
    }
    out[idx] = outv;
}

// ---------------------------------------------------------------------------
extern "C" void kernel_launch(void* const* d_in, const int* in_sizes, int n_in,
                              void* d_out, int out_size, void* d_ws, size_t ws_size,
                              hipStream_t stream)
{
    const float* x      = (const float*)d_in[0];
    const float* w1f_ih = (const float*)d_in[1];
    const float* w1f_hh = (const float*)d_in[2];
    const float* b1f_ih = (const float*)d_in[3];
    const float* b1f_hh = (const float*)d_in[4];
    const float* w1b_ih = (const float*)d_in[5];
    const float* w1b_hh = (const float*)d_in[6];
    const float* b1b_ih = (const float*)d_in[7];
    const float* b1b_hh = (const float*)d_in[8];
    const float* w2f_ih = (const float*)d_in[9];
    const float* w2f_hh = (const float*)d_in[10];
    const float* b2f_ih = (const float*)d_in[11];
    const float* b2f_hh = (const float*)d_in[12];
    const float* w2b_ih = (const float*)d_in[13];
    const float* w2b_hh = (const float*)d_in[14];
    const float* b2b_ih = (const float*)d_in[15];
    const float* b2b_hh = (const float*)d_in[16];
    const float* wd1    = (const float*)d_in[17];
    const float* bd1    = (const float*)d_in[18];
    const float* wd2    = (const float*)d_in[19];
    const float* bd2    = (const float*)d_in[20];
    const float* wo     = (const float*)d_in[21];
    const float* bo     = (const float*)d_in[22];
    float* out = (float*)d_out;

    // Workspace: y1 bf16 [T][128][140][16] (192.7 MB) + y2 bf16 [B][T][42] (57.8 MB)
    const size_t y1_elems = (size_t)Tz * 128 * 2240;
    const size_t y2_elems = (size_t)Bz * Tz * 42;
    if (ws_size < (y1_elems + y2_elems) * 2) return;

    unsigned short* y1 = (unsigned short*)d_ws;
    unsigned short* y2 = y1 + y1_elems;

    hipLaunchKernelGGL(k_lstm1, dim3(256), dim3(1024), 0, stream,
                       x, w1f_ih, w1f_hh, b1f_ih, b1f_hh,
                       w1b_ih, w1b_hh, b1b_ih, b1b_hh, y1);
    hipLaunchKernelGGL(k_lstm2, dim3(256), dim3(512), 0, stream,
                       y1, w2f_ih, w2f_hh, b2f_ih, b2f_hh,
                       w2b_ih, w2b_hh, b2b_ih, b2b_hh, y2);
    hipLaunchKernelGGL(k_dense, dim3((Bz * Tz + 255) / 256), dim3(256), 0, stream,
                       y2, wd1, bd1, wd2, bd2, wo, bo, out);
}

// Round 12
// 718.959 us; speedup vs baseline: 1.8443x; 1.0023x over previous
//
#include <hip/hip_runtime.h>

// Problem constants
#define Bz 2048
#define Tz 336
#define Fz 10
#define H1 70
#define H2 21

typedef __attribute__((ext_vector_type(8))) short short8;   // 8 bf16 = 4 VGPR
typedef __attribute__((ext_vector_type(4))) float float4v;  // MFMA acc

#define MFMA16(a, b, c) __builtin_amdgcn_mfma_f32_16x16x32_bf16((a), (b), (c), 0, 0, 0)

// LDS-only barrier (composable-kernel idiom): orders LDS across the block
// WITHOUT draining vmcnt — __syncthreads() would stall on the y1/y2 global
// stores (never read in-kernel) every step (~200-900 cyc store-ack, m126).
__device__ __forceinline__ void sync_lds() {
    asm volatile("s_waitcnt lgkmcnt(0)\n\ts_barrier" ::: "memory");
}

__device__ __forceinline__ float sigf(float x) {
    return 1.0f / (1.0f + __expf(-x));
}
__device__ __forceinline__ float tanhfast(float x) {
    float t = __expf(2.0f * x);
    return 1.0f - 2.0f / (t + 1.0f);
}
__device__ __forceinline__ unsigned short f2bf(float v) {
    unsigned int u = __float_as_uint(v);
    u += 0x7FFFu + ((u >> 16) & 1u);
    return (unsigned short)(u >> 16);
}
__device__ __forceinline__ float bf2f(unsigned short s) {
    return __uint_as_float(((unsigned int)s) << 16);
}

// Fragment-order LDS offset (in shorts) for (col m, k):
// (m, k) lives at ((k>>3)*16 + m)*8 + (k&7)
__device__ __forceinline__ int frag_off(int m, int k) {
    return (k >> 3) * 128 + m * 8 + (k & 7);
}

// ---------------------------------------------------------------------------
// Layer 1 (MFMA, D = W x h): input F=10, hidden 70.  [round-11 structure]
// Grid 256 = 2 dir x 128 tiles of 16 batch rows. 1024 threads = 16 waves.
// 18 M-tiles: wave w owns tile w; waves 0,1 also own tiles 16,17.
//   K: 0..69 = h, 70..79 = x, 80 = bias slot (B col 1.0), 81..95 = 0.
// h bf16 hi-only in LDS; W hi+lo in registers (6 MFMA/tile). ONE LDS-only
// barrier per step (sync_lds), double-buffered B-LDS, x prefetch depth 2,
// step loop unrolled x2 (pp literal), strided pointers.
// y1 layout: [T][128][140][16] bf16.
// ---------------------------------------------------------------------------
__global__ __launch_bounds__(1024, 4) void k_lstm1(
    const float* __restrict__ x,
    const float* __restrict__ wih_f, const float* __restrict__ whh_f,
    const float* __restrict__ bih_f, const float* __restrict__ bhh_f,
    const float* __restrict__ wih_b, const float* __restrict__ whh_b,
    const float* __restrict__ bih_b, const float* __restrict__ bhh_b,
    unsigned short* __restrict__ y1)
{
    __shared__ short hB_hi[2][1536];   // 96 k x 16 batch, frag order, dbuf

    const int tb  = blockIdx.x & 127;
    const int dir = blockIdx.x >> 7;
    const int b0  = tb << 4;
    const float* wih = dir ? wih_b : wih_f;
    const float* whh = dir ? whh_b : whh_f;
    const float* bih = dir ? bih_b : bih_f;
    const float* bhh = dir ? bhh_b : bhh_f;

    const int tid  = threadIdx.x;
    const int wv   = tid >> 6;
    const int lane = tid & 63;
    const int n    = lane & 15;
    const int quad = lane >> 4;
    const int NT1  = (wv < 2) ? 2 : 1;   // tiles this wave owns

    // ---- W-side (A-operand) preload, hi+lo bf16 ----
    short8 whi[2][3], wlo[2][3];
    const int g_ = n & 3;
#pragma unroll
    for (int tt = 0; tt < 2; ++tt) {
        if (tt < NT1) {
            const int p  = wv + 16 * tt;
            const int uu = 4 * p + (n >> 2);
#pragma unroll
            for (int q = 0; q < 3; ++q) {
#pragma unroll
                for (int j = 0; j < 8; ++j) {
                    int k = q * 32 + quad * 8 + j;
                    float v = 0.0f;
                    if (uu < H1) {
                        int row = g_ * H1 + uu;
                        if (k < H1)        v = whh[row * H1 + k];
                        else if (k < 80)   v = wih[row * Fz + (k - H1)];
                        else if (k == 80)  v = bih[row] + bhh[row];
                    }
                    unsigned short hi = f2bf(v);
                    unsigned short lo = f2bf(v - bf2f(hi));
                    whi[tt][q][j] = (short)hi;
                    wlo[tt][q][j] = (short)lo;
                }
            }
        }
    }

    // ---- init LDS ----
    for (int e = tid; e < 1536; e += 1024) {
        hB_hi[0][e] = 0; hB_hi[1][e] = 0;
    }
    __syncthreads();
    if (tid < 16) {
        int off = 1280 + tid * 8;       // frag_off(tid, 80)
        hB_hi[0][off] = (short)0x3F80;  // bf16(1.0) bias const
        hB_hi[1][off] = (short)0x3F80;
    }

    // ---- stagers: es in [0,160) -> (m, f), threads 864..1023 ----
    const int es = tid - 864;
    const bool stg = (es >= 0 && es < 160);
    int sm = 0, sf = 0;
    if (stg) { sm = es / Fz; sf = es % Fz; }

    const int tstep = dir ? -1 : 1;
    const int t0    = dir ? (Tz - 1) : 0;

    // prologue: stage x(t0) into buf 0; preload x(t1) into regs
    float xv = 0.0f;
    if (stg) {
        float v = x[((size_t)(b0 + sm) * Tz + t0) * Fz + sf];
        hB_hi[0][frag_off(sm, H1 + sf)] = (short)f2bf(v);
        xv = x[((size_t)(b0 + sm) * Tz + t0 + tstep) * Fz + sf];
    }
    // strided pointers (advance by tstep*stride per step)
    const float* xp = x + ((size_t)(b0 + sm) * Tz + t0 + 2 * tstep) * Fz + sf;
    const ptrdiff_t xinc = (ptrdiff_t)tstep * Fz;
    unsigned short* yp = y1 + (((size_t)t0 * 128 + tb) * 140 + dir * H1) * 16 + n;
    const ptrdiff_t yinc = (ptrdiff_t)tstep * (140 * 128 * 16);

    // hoisted LDS write offsets (loop-invariant)
    const int xoff = frag_off(sm, H1 + sf);
    int hoff[2];
#pragma unroll
    for (int tt = 0; tt < 2; ++tt) hoff[tt] = frag_off(n, 4 * (wv + 16 * tt) + quad);

    float cst[2];
    cst[0] = 0.0f; cst[1] = 0.0f;

    // one step; pp is a literal at each call site -> all LDS addrs invariant
    auto body = [&](int step, const int pp) __attribute__((always_inline)) {
        sync_lds();   // buf[pp] complete, buf[pp^1] free (LDS-only barrier)

        if (stg && step + 1 < Tz) {
            hB_hi[pp ^ 1][xoff] = (short)f2bf(xv);
        }
        if (stg && step + 2 < Tz) {
            xv = *xp;
        }

        short8 bhi[3];
#pragma unroll
        for (int q = 0; q < 3; ++q)
            bhi[q] = *(const short8*)&hB_hi[pp][q * 512 + lane * 8];

        float4v accA[2], accB[2];
#pragma unroll
        for (int tt = 0; tt < 2; ++tt) {
            accA[tt] = (float4v){0.f, 0.f, 0.f, 0.f};
            accB[tt] = (float4v){0.f, 0.f, 0.f, 0.f};
        }
#pragma unroll
        for (int tt = 0; tt < 2; ++tt) {
            if (tt < NT1) {
                accA[tt] = MFMA16(whi[tt][0], bhi[0], accA[tt]);
                accB[tt] = MFMA16(wlo[tt][0], bhi[0], accB[tt]);
                accA[tt] = MFMA16(whi[tt][1], bhi[1], accA[tt]);
                accB[tt] = MFMA16(wlo[tt][1], bhi[1], accB[tt]);
                accA[tt] = MFMA16(whi[tt][2], bhi[2], accA[tt]);
                accB[tt] = MFMA16(wlo[tt][2], bhi[2], accB[tt]);
            }
        }

#pragma unroll
        for (int tt = 0; tt < 2; ++tt) {
            if (tt < NT1) {
                const int u = 4 * (wv + 16 * tt) + quad;
                if (u < H1) {
                    float gi = accA[tt][0] + accB[tt][0];
                    float gf = accA[tt][1] + accB[tt][1];
                    float gc = accA[tt][2] + accB[tt][2];
                    float go = accA[tt][3] + accB[tt][3];
                    float cn = sigf(gf) * cst[tt] + sigf(gi) * tanhfast(gc);
                    float h  = sigf(go) * tanhfast(cn);
                    cst[tt] = cn;
                    unsigned short hh = f2bf(h);
                    hB_hi[pp ^ 1][hoff[tt]] = (short)hh;
                    yp[u * 16] = hh;
                }
            }
        }
        xp += xinc;
        yp += yinc;
    };

    for (int step = 0; step < Tz; step += 2) {
        body(step, 0);
        body(step + 1, 1);
    }
}

// ---------------------------------------------------------------------------
// Layer 2 (MFMA, D = W x h): input 140 (bf16 y1 [T][128][140][16]), hidden 21.
// [round-11 structure] Grid 256 = 2 dir x 128 tiles of 16 rows. 512 thr = 8
// waves: waves 0..5 compute tile p = wv (u = 4p+quad); threads 232..511
// stage x (16B vector loads). K: 0..20 = h, 21 = bias, 32..171 = x.
// h/x hi-only; W-lo for chunk 0 only: 7 MFMA/wave. LDS-only barrier.
// ---------------------------------------------------------------------------
__global__ __launch_bounds__(512, 2) void k_lstm2(
    const unsigned short* __restrict__ y1,
    const float* __restrict__ wih_f, const float* __restrict__ whh_f,
    const float* __restrict__ bih_f, const float* __restrict__ bhh_f,
    const float* __restrict__ wih_b, const float* __restrict__ whh_b,
    const float* __restrict__ bih_b, const float* __restrict__ bhh_b,
    unsigned short* __restrict__ y2)   // [B][T][42] bf16
{
    __shared__ short hB_hi[2][3072];   // 192 k x 16 batch

    const int tb  = blockIdx.x & 127;
    const int dir = blockIdx.x >> 7;
    const int b0  = tb << 4;
    const float* wih = dir ? wih_b : wih_f;
    const float* whh = dir ? whh_b : whh_f;
    const float* bih = dir ? bih_b : bih_f;
    const float* bhh = dir ? bhh_b : bhh_f;

    const int tid  = threadIdx.x;
    const int wv   = tid >> 6;
    const int lane = tid & 63;
    const int n    = lane & 15;
    const int quad = lane >> 4;
    const bool comp = (wv < 6);

    // ---- W-side preload (waves 0..5): hi all chunks, lo chunk 0 ----
    short8 whi[6], wlo0;
    const int g_ = n & 3;
    if (comp) {
        const int uu = 4 * wv + (n >> 2);
#pragma unroll
        for (int q = 0; q < 6; ++q) {
#pragma unroll
            for (int j = 0; j < 8; ++j) {
                int k = q * 32 + quad * 8 + j;
                float v = 0.0f;
                if (uu < H2) {
                    int row = g_ * H2 + uu;
                    if (k < H2)                   v = whh[row * H2 + k];
                    else if (k == 21)             v = bih[row] + bhh[row];
                    else if (k >= 32 && k < 172)  v = wih[row * 140 + (k - 32)];
                }
                unsigned short hi = f2bf(v);
                whi[q][j] = (short)hi;
                if (q == 0) wlo0[j] = (short)f2bf(v - bf2f(hi));
            }
        }
    }

    // ---- init LDS ----
    for (int e = tid; e < 3072; e += 512) { hB_hi[0][e] = 0; hB_hi[1][e] = 0; }
    __syncthreads();
    if (tid < 16) {
        int off = frag_off(tid, 21);
        hB_hi[0][off] = (short)0x3F80;   // bias const 1.0
        hB_hi[1][off] = (short)0x3F80;
    }

    // ---- stager threads: es in [0,280); each loads 16B (8 ushorts) ----
    const int es = tid - 232;
    const bool stg = (es >= 0 && es < 280);

    const int tstep = dir ? -1 : 1;
    const int t0    = dir ? (Tz - 1) : 0;

    // prologue: stage x(t0) into buf 0; preload x(t1)
    short8 xr = (short8){0,0,0,0,0,0,0,0};
    if (stg) {
        short8 v = *(const short8*)(y1 + ((size_t)t0 * 128 + tb) * 2240 + es * 8);
#pragma unroll
        for (int j = 0; j < 8; ++j) {
            int idx = es * 8 + j;
            hB_hi[0][frag_off(idx & 15, 32 + (idx >> 4))] = v[j];
        }
        xr = *(const short8*)(y1 + ((size_t)(t0 + tstep) * 128 + tb) * 2240 + es * 8);
    }
    // strided pointers
    const unsigned short* srcp =
        y1 + ((size_t)(t0 + 2 * tstep) * 128 + tb) * 2240 + es * 8;
    const ptrdiff_t sinc = (ptrdiff_t)tstep * (128 * 2240);
    unsigned short* yp2 = y2 + ((size_t)(b0 + n) * Tz + t0) * 42 + dir * H2;
    const ptrdiff_t yinc = (ptrdiff_t)tstep * 42;

    // hoisted LDS offsets
    int xoffs[8];
#pragma unroll
    for (int j = 0; j < 8; ++j) {
        int idx = es * 8 + j;
        xoffs[j] = frag_off(idx & 15, 32 + (idx >> 4));
    }
    const int u     = 4 * wv + quad;
    const int hoffc = frag_off(n, (u < H2) ? u : 0);

    float cst = 0.0f;

    auto body = [&](int step, const int pp) __attribute__((always_inline)) {
        sync_lds();   // LDS-only barrier

        if (stg && step + 1 < Tz) {
#pragma unroll
            for (int j = 0; j < 8; ++j)
                hB_hi[pp ^ 1][xoffs[j]] = xr[j];
        }
        if (stg && step + 2 < Tz) {
            xr = *(const short8*)srcp;
        }

        if (comp) {
            short8 bhi[6];
#pragma unroll
            for (int q = 0; q < 6; ++q)
                bhi[q] = *(const short8*)&hB_hi[pp][q * 512 + lane * 8];

            float4v accA = (float4v){0.f, 0.f, 0.f, 0.f};
            float4v accB = (float4v){0.f, 0.f, 0.f, 0.f};
            accA = MFMA16(whi[0], bhi[0], accA);
            accB = MFMA16(wlo0,   bhi[0], accB);
            accA = MFMA16(whi[2], bhi[2], accA);
            accB = MFMA16(whi[1], bhi[1], accB);
            accA = MFMA16(whi[4], bhi[4], accA);
            accB = MFMA16(whi[3], bhi[3], accB);
            accB = MFMA16(whi[5], bhi[5], accB);

            if (u < H2) {
                float gi = accA[0] + accB[0];
                float gf = accA[1] + accB[1];
                float gc = accA[2] + accB[2];
                float go = accA[3] + accB[3];
                float cn = sigf(gf) * cst + sigf(gi) * tanhfast(gc);
                float h  = sigf(go) * tanhfast(cn);
                cst = cn;
                unsigned short hh = f2bf(h);
                hB_hi[pp ^ 1][hoffc] = (short)hh;
                yp2[u] = hh;
            }
        }
        srcp += sinc;
        yp2  += yinc;
    };

    for (int step = 0; step < Tz; step += 2) {
        body(step, 0);
        body(step + 1, 1);
    }
}

// ---------------------------------------------------------------------------
// Dense head: thread per (b,t). Weights via uniform scalar loads.
// ---------------------------------------------------------------------------
__global__ __launch_bounds__(256) void k_dense(
    const unsigned short* __restrict__ y2,
    const float* __restrict__ wd1, const float* __restrict__ bd1,
    const float* __restrict__ wd2, const float* __restrict__ bd2,
    const float* __restrict__ wo,  const float* __restrict__ bo,
    float* __restrict__ out)
{
    int idx = blockIdx.x * 256 + threadIdx.x;
    if (idx >= Bz * Tz) return;
    const unsigned int* row = (const unsigned int*)&y2[(size_t)idx * 42];

    float v[42];
#pragma unroll
    for (int j = 0; j < 21; ++j) {
        unsigned int p = row[j];
        v[2 * j]     = bf2f((unsigned short)(p & 0xFFFFu));
        v[2 * j + 1] = bf2f((unsigned short)(p >> 16));
    }

    float h1[30];
#pragma unroll
    for (int o = 0; o < 30; ++o) {
        float s = bd1[o];
#pragma unroll
        for (int j = 0; j < 42; ++j) s = fmaf(v[j], wd1[o * 42 + j], s);
        h1[o] = fmaxf(s, 0.0f);
    }
    float outv = bo[0];
#pragma unroll
    for (int o = 0; o < 20; ++o) {
        float s = bd2[o];
#pragma unroll
        for (int j = 0; j < 30; ++j) s = fmaf(h1[j], wd2[o * 30 + j], s);
        outv = fmaf(fmaxf(s, 0.0f), wo[o], outv);
    }
    out[idx] = outv;
}

// ---------------------------------------------------------------------------
extern "C" void kernel_launch(void* const* d_in, const int* in_sizes, int n_in,
                              void* d_out, int out_size, void* d_ws, size_t ws_size,
                              hipStream_t stream)
{
    const float* x      = (const float*)d_in[0];
    const float* w1f_ih = (const float*)d_in[1];
    const float* w1f_hh = (const float*)d_in[2];
    const float* b1f_ih = (const float*)d_in[3];
    const float* b1f_hh = (const float*)d_in[4];
    const float* w1b_ih = (const float*)d_in[5];
    const float* w1b_hh = (const float*)d_in[6];
    const float* b1b_ih = (const float*)d_in[7];
    const float* b1b_hh = (const float*)d_in[8];
    const float* w2f_ih = (const float*)d_in[9];
    const float* w2f_hh = (const float*)d_in[10];
    const float* b2f_ih = (const float*)d_in[11];
    const float* b2f_hh = (const float*)d_in[12];
    const float* w2b_ih = (const float*)d_in[13];
    const float* w2b_hh = (const float*)d_in[14];
    const float* b2b_ih = (const float*)d_in[15];
    const float* b2b_hh = (const float*)d_in[16];
    const float* wd1    = (const float*)d_in[17];
    const float* bd1    = (const float*)d_in[18];
    const float* wd2    = (const float*)d_in[19];
    const float* bd2    = (const float*)d_in[20];
    const float* wo     = (const float*)d_in[21];
    const float* bo     = (const float*)d_in[22];
    float* out = (float*)d_out;

    // Workspace: y1 bf16 [T][128][140][16] (192.7 MB) + y2 bf16 [B][T][42] (57.8 MB)
    const size_t y1_elems = (size_t)Tz * 128 * 2240;
    const size_t y2_elems = (size_t)Bz * Tz * 42;
    if (ws_size < (y1_elems + y2_elems) * 2) return;

    unsigned short* y1 = (unsigned short*)d_ws;
    unsigned short* y2 = y1 + y1_elems;

    hipLaunchKernelGGL(k_lstm1, dim3(256), dim3(1024), 0, stream,
                       x, w1f_ih, w1f_hh, b1f_ih, b1f_hh,
                       w1b_ih, w1b_hh, b1b_ih, b1b_hh, y1);
    hipLaunchKernelGGL(k_lstm2, dim3(256), dim3(512), 0, stream,
                       y1, w2f_ih, w2f_hh, b2f_ih, b2f_hh,
                       w2b_ih, w2b_hh, b2b_ih, b2b_hh, y2);
    hipLaunchKernelGGL(k_dense, dim3((Bz * Tz + 255) / 256), dim3(256), 0, stream,
                       y2, wd1, bd1, wd2, bd2, wo, bo, out);
}